// Round 3
// baseline (209.991 us; speedup 1.0000x reference)
//
#include <hip/hip_runtime.h>
#include <math.h>

// Converse2D (USRNet closed-form prox), s=2, B=4, C=64, H=W=128, K=5.
// Per (b,c): fwd 128x128 FFT (radix-8/16 fused stages in regs), spectrum kept in
// VGPRs, two {K-mult + inv FFT} passes packing the 4 output polyphases.
// K precomputed analytically; stored in 2D-bit-reversed order via coalesced stores.

struct cx { float x, y; };
__device__ __forceinline__ cx cmul(cx a, cx b){ return cx{a.x*b.x - a.y*b.y, a.x*b.y + a.y*b.x}; }
__device__ __forceinline__ cx cadd(cx a, cx b){ return cx{a.x+b.x, a.y+b.y}; }
__device__ __forceinline__ cx csub(cx a, cx b){ return cx{a.x-b.x, a.y-b.y}; }
__device__ __forceinline__ cx cconj(cx a){ return cx{a.x, -a.y}; }
__device__ __forceinline__ cx cscale(cx a, float s){ return cx{a.x*s, a.y*s}; }

__device__ __forceinline__ float2 cmulf(float2 a, float2 b){
    return make_float2(a.x*b.x - a.y*b.y, a.x*b.y + a.y*b.x);
}
__device__ __forceinline__ float2 cmulcf(float2 a, float2 b){ // a * conj(b)
    return make_float2(a.x*b.x + a.y*b.y, a.y*b.x - a.x*b.y);
}
__device__ __forceinline__ float2 caddf(float2 a, float2 b){ return make_float2(a.x+b.x, a.y+b.y); }
__device__ __forceinline__ float2 csubf(float2 a, float2 b){ return make_float2(a.x-b.x, a.y-b.y); }

// Forward DIF butterfly: u' = u+v ; v' = (u-v)*w
__device__ __forceinline__ void bf(float2 &u, float2 &v, float2 w){
    float2 a = caddf(u, v); float2 d = csubf(u, v); u = a; v = cmulf(d, w);
}
__device__ __forceinline__ void bf1(float2 &u, float2 &v){
    float2 a = caddf(u, v); float2 d = csubf(u, v); u = a; v = d;
}
// Inverse DIT butterfly with w given UN-conjugated: t = v*conj(w); u' = u+t; v' = u-t
__device__ __forceinline__ void bi(float2 &u, float2 &v, float2 w){
    float2 t = cmulcf(v, w); float2 a = caddf(u, t); float2 d = csubf(u, t); u = a; v = d;
}
__device__ __forceinline__ void bi1(float2 &u, float2 &v){
    float2 a = caddf(u, v); float2 d = csubf(u, v); u = a; v = d;
}

// TW[k] = e^{-2*pi*i*k/128} constants
#define C_TW1  make_float2(0.99879545620517239f, -0.04906767432741801f)
#define C_TW2  make_float2(0.99518472667219693f, -0.09801714032956060f)
#define C_TW3  make_float2(0.98917650996478101f, -0.14673047445536175f)
#define C_TW8  make_float2(0.92387953251128674f, -0.38268343236508977f)
#define C_TW16 make_float2(0.70710678118654752f, -0.70710678118654752f)
#define C_TW24 make_float2(0.38268343236508977f, -0.92387953251128674f)
#define C_TW32 make_float2(0.0f, -1.0f)
#define C_TW40 make_float2(-0.38268343236508977f, -0.92387953251128674f)
#define C_TW48 make_float2(-0.70710678118654752f, -0.70710678118654752f)
#define C_TW56 make_float2(-0.92387953251128674f, -0.38268343236508977f)

// ---------------- K precompute (analytic transfer function) ----------------
// TAB[k] = e^{-2*pi*i*k/256}
__device__ __forceinline__ void compute_H_tab(const float* __restrict__ wc, float lam,
                                              int q, int r, const float2* __restrict__ TAB,
                                              cx H[4])
{
    cx er[5], eq[5];
    #pragma unroll
    for (int t = 0; t < 5; ++t) {
        float2 a = TAB[(r * (t - 2)) & 255];
        er[t] = cx{a.x, a.y};
        float2 b = TAB[(q * (t - 2)) & 255];
        eq[t] = cx{b.x, b.y};
    }
    cx P0[5], P1[5];
    #pragma unroll
    for (int a = 0; a < 5; ++a) {
        cx p0{0.f,0.f}, p1{0.f,0.f};
        #pragma unroll
        for (int b = 0; b < 5; ++b) {
            cx t = cscale(er[b], wc[a*5 + b]);
            p0 = cadd(p0, t);
            p1 = (b & 1) ? csub(p1, t) : cadd(p1, t);
        }
        P0[a] = p0; P1[a] = p1;
    }
    cx F[2][2];
    F[0][0]=cx{0.f,0.f}; F[0][1]=cx{0.f,0.f}; F[1][0]=cx{0.f,0.f}; F[1][1]=cx{0.f,0.f};
    #pragma unroll
    for (int a = 0; a < 5; ++a) {
        cx t0 = cmul(eq[a], P0[a]);
        cx t1 = cmul(eq[a], P1[a]);
        F[0][0] = cadd(F[0][0], t0); F[0][1] = cadd(F[0][1], t1);
        if (a & 1) { F[1][0] = csub(F[1][0], t0); F[1][1] = csub(F[1][1], t1); }
        else       { F[1][0] = cadd(F[1][0], t0); F[1][1] = cadd(F[1][1], t1); }
    }
    float cq = TAB[q].x, sq = TAB[q].y;
    float cr = TAB[r].x, sr = TAB[r].y;
    cx Du[2] = { cx{1.f+cq,  sq}, cx{1.f-cq, -sq} };
    cx Dv[2] = { cx{1.f+cr,  sr}, cx{1.f-cr, -sr} };
    cx R[2][2];
    float invW = 0.f;
    cx M{0.f,0.f};
    #pragma unroll
    for (int i = 0; i < 2; ++i)
      #pragma unroll
      for (int k = 0; k < 2; ++k) {
        cx fb = F[i][k];
        cx Rik = cadd(cconj(fb), cscale(cmul(Du[i], Dv[k]), lam));
        R[i][k] = Rik;
        invW += 0.25f * (fb.x*fb.x + fb.y*fb.y);
        M = cadd(M, cscale(cmul(fb, Rik), 0.25f));
      }
    cx V = cscale(M, 1.0f / (invW + lam));
    float inv_lam = 1.0f / lam;
    cx G[2][2];
    #pragma unroll
    for (int i = 0; i < 2; ++i)
      #pragma unroll
      for (int k = 0; k < 2; ++k)
        G[i][k] = cscale(csub(R[i][k], cmul(cconj(F[i][k]), V)), inv_lam);

    cx G00 = G[0][0], G01 = G[0][1], G10 = G[1][0], G11 = G[1][1];
    cx Gh00 = cadd(cadd(G00,G01), cadd(G10,G11));
    cx Gh01 = cadd(csub(G00,G01), csub(G10,G11));
    cx Gh10 = csub(cadd(G00,G01), cadd(G10,G11));
    cx Gh11 = csub(csub(G00,G01), csub(G10,G11));
    cx phq = cx{cq, -sq};
    cx phr = cx{cr, -sr};
    H[0] = Gh00;
    H[1] = cmul(Gh01, phr);
    H[2] = cmul(Gh10, phq);
    H[3] = cmul(Gh11, cmul(phq, phr));
}

__global__ __launch_bounds__(256)
void precompute_K(const float* __restrict__ weight, const float* __restrict__ lam_ptr,
                  float2* __restrict__ KA, float2* __restrict__ KB)
{
    __shared__ float2 TAB[256];
    __shared__ float WC[25];
    const int tid = threadIdx.x;
    {
        float s_, c_;
        __sincosf(-6.28318530717958647692f * (float)tid * (1.0f/256.0f), &s_, &c_);
        TAB[tid] = make_float2(c_, s_);
    }
    const int c = blockIdx.x >> 3;           // 512 blocks: 8 per channel
    if (tid < 25) WC[tid] = weight[c*25 + tid];
    __syncthreads();
    const float lam = lam_ptr[0];
    const int nbase = (blockIdx.x & 7) * 2048;
    const float scale = 1.0f / 65536.0f;     // ifft 1/(128*128) and 1/4 polyphase mean

    #pragma unroll 1
    for (int k = 0; k < 8; ++k) {
        int n = nbase + k*256 + tid;         // linear STORE index -> coalesced
        int row = n >> 7, col = n & 127;
        int q = (int)(__brev((unsigned)row) >> 25);  // freq coords = bitrev of store pos
        int r = (int)(__brev((unsigned)col) >> 25);
        cx H[4];
        compute_H_tab(WC, lam, q, r, TAB, H);
        float2 kAv = make_float2((H[0].x - H[1].y)*scale, (H[0].y + H[1].x)*scale);
        float2 kBv = make_float2((H[2].x - H[3].y)*scale, (H[2].y + H[3].x)*scale);
        KA[(c << 14) + n] = kAv;
        KB[(c << 14) + n] = kBv;
    }
}

// ---------------- main kernel ----------------
#define ST2 130   // float2 stride: even (16B-aligned rows for b128), pad 2 vs 128

__global__ __launch_bounds__(1024)
void converse_main(const float* __restrict__ x, const float* __restrict__ bias,
                   const float2* __restrict__ KA, const float2* __restrict__ KB,
                   float* __restrict__ out)
{
    __shared__ float2 S[128 * ST2];
    const int tid = threadIdx.x;
    const int bc  = blockIdx.x;       // [0,256) = b*64 + c
    const int c   = bc & 63;
    const float TWO_PI_N = 6.28318530717958647692f / 128.0f;

    // ---- load x[b,c] as {x,0} ----
    const float4* xp4 = (const float4*)(x + (size_t)bc * 16384);
    #pragma unroll
    for (int it = 0; it < 4; ++it) {
        int g = it * 1024 + tid;
        float4 v = xp4[g];
        int row = g >> 5, cg = g & 31;
        float4* p = (float4*)&S[row * ST2 + cg * 4];
        p[0] = make_float4(v.x, 0.f, v.y, 0.f);
        p[1] = make_float4(v.z, 0.f, v.w, 0.f);
    }
    __syncthreads();

    // ---- fwd rows, stages 0,1,2: dual octet j=2J,2J+1, cols j+16m ----
    {
        const int line = tid >> 3, J = tid & 7;
        float2* base = &S[line * ST2 + 2 * J];
        float2 e[2][8];
        #pragma unroll
        for (int m = 0; m < 8; ++m) {
            float4 v = *(float4*)(base + 16 * m);
            e[0][m] = make_float2(v.x, v.y);
            e[1][m] = make_float2(v.z, v.w);
        }
        float sj, cj;
        __sincosf(-TWO_PI_N * (float)(2 * J), &sj, &cj);
        float2 w1d[2];
        w1d[0] = make_float2(cj, sj);
        w1d[1] = cmulf(w1d[0], C_TW1);
        #pragma unroll
        for (int d = 0; d < 2; ++d) {
            float2 wa = w1d[d];
            float2 w2 = cmulf(wa, wa);
            float2 w4 = cmulf(w2, w2);
            // s=0: (m,m+4), w = TW[j+16m] = wa*TW[16m]
            bf(e[d][0], e[d][4], wa);
            bf(e[d][1], e[d][5], cmulf(wa, C_TW16));
            bf(e[d][2], e[d][6], cmulf(wa, C_TW32));
            bf(e[d][3], e[d][7], cmulf(wa, C_TW48));
            // s=1: (m,m+2), w = TW[2j+32(m&1)]
            float2 w2b = cmulf(w2, C_TW32);
            bf(e[d][0], e[d][2], w2);  bf(e[d][1], e[d][3], w2b);
            bf(e[d][4], e[d][6], w2);  bf(e[d][5], e[d][7], w2b);
            // s=2: (m,m+1), w = TW[4j]
            bf(e[d][0], e[d][1], w4);  bf(e[d][2], e[d][3], w4);
            bf(e[d][4], e[d][5], w4);  bf(e[d][6], e[d][7], w4);
        }
        #pragma unroll
        for (int m = 0; m < 8; ++m)
            *(float4*)(base + 16 * m) = make_float4(e[0][m].x, e[0][m].y, e[1][m].x, e[1][m].y);
    }
    __syncthreads();

    // ---- fwd rows, stages 3,4,5,6: radix-16 over cols 16b..16b+15, const twiddles ----
    {
        const int line = tid >> 3, b = tid & 7;
        float2* base = &S[line * ST2 + 16 * b];
        float2 e[16];
        #pragma unroll
        for (int k = 0; k < 8; ++k) {
            float4 v = *(float4*)(base + 2 * k);
            e[2*k]   = make_float2(v.x, v.y);
            e[2*k+1] = make_float2(v.z, v.w);
        }
        // s=3: (m,m+8), w = TW[8m]
        bf1(e[0], e[8]);
        bf(e[1], e[9],  C_TW8);  bf(e[2], e[10], C_TW16); bf(e[3], e[11], C_TW24);
        bf(e[4], e[12], C_TW32); bf(e[5], e[13], C_TW40); bf(e[6], e[14], C_TW48);
        bf(e[7], e[15], C_TW56);
        // s=4: (m,m+4), w = TW[16(m&3)]
        #pragma unroll
        for (int h = 0; h < 16; h += 8) {
            bf1(e[h+0], e[h+4]);
            bf(e[h+1], e[h+5], C_TW16);
            bf(e[h+2], e[h+6], C_TW32);
            bf(e[h+3], e[h+7], C_TW48);
        }
        // s=5: (m,m+2), w = TW[32(m&1)]
        #pragma unroll
        for (int q = 0; q < 16; q += 4) {
            bf1(e[q+0], e[q+2]);
            bf(e[q+1], e[q+3], C_TW32);
        }
        // s=6: (m,m+1), w=1
        #pragma unroll
        for (int p = 0; p < 16; p += 2) bf1(e[p], e[p+1]);
        #pragma unroll
        for (int k = 0; k < 8; ++k)
            *(float4*)(base + 2 * k) = make_float4(e[2*k].x, e[2*k].y, e[2*k+1].x, e[2*k+1].y);
    }
    __syncthreads();

    // ---- fwd cols, stages 0,1,2,3: radix-16 over rows j+8m ----
    {
        const int col = tid & 127, j = tid >> 7;
        float2 e[16];
        #pragma unroll
        for (int m = 0; m < 16; ++m) e[m] = S[(j + 8*m) * ST2 + col];
        float sj, cj;
        __sincosf(-TWO_PI_N * (float)j, &sj, &cj);
        float2 w1 = make_float2(cj, sj);
        float2 w2 = cmulf(w1, w1);
        float2 w4 = cmulf(w2, w2);
        float2 w8 = cmulf(w4, w4);
        // s=0: (m,m+8), w = TW[j+8m] = w1*TW[8m]
        bf(e[0], e[8],  w1);
        bf(e[1], e[9],  cmulf(w1, C_TW8));
        bf(e[2], e[10], cmulf(w1, C_TW16));
        bf(e[3], e[11], cmulf(w1, C_TW24));
        bf(e[4], e[12], cmulf(w1, C_TW32));
        bf(e[5], e[13], cmulf(w1, C_TW40));
        bf(e[6], e[14], cmulf(w1, C_TW48));
        bf(e[7], e[15], cmulf(w1, C_TW56));
        // s=1: (m,m+4), w = TW[2j+16(m&3)] = w2*TW[16(m&3)]
        #pragma unroll
        for (int h = 0; h < 16; h += 8) {
            bf(e[h+0], e[h+4], w2);
            bf(e[h+1], e[h+5], cmulf(w2, C_TW16));
            bf(e[h+2], e[h+6], cmulf(w2, C_TW32));
            bf(e[h+3], e[h+7], cmulf(w2, C_TW48));
        }
        // s=2: (m,m+2), w = TW[4j+32(m&1)]
        float2 w4b = cmulf(w4, C_TW32);
        #pragma unroll
        for (int q = 0; q < 16; q += 4) {
            bf(e[q+0], e[q+2], w4);
            bf(e[q+1], e[q+3], w4b);
        }
        // s=3: (m,m+1), w = TW[8j]
        #pragma unroll
        for (int p = 0; p < 16; p += 2) bf(e[p], e[p+1], w8);
        #pragma unroll
        for (int m = 0; m < 16; ++m) S[(j + 8*m) * ST2 + col] = e[m];
    }
    __syncthreads();

    // ---- capture: fwd col stages 4,5,6 in regs; spectrum X kept for both passes ----
    const int colX = tid & 127;
    const int b0   = tid >> 7;
    float2 X[2][8];
    #pragma unroll
    for (int it = 0; it < 2; ++it) {
        const int rb = 8 * (b0 + 8 * it);
        float2 e[8];
        #pragma unroll
        for (int m = 0; m < 8; ++m) e[m] = S[(rb + m) * ST2 + colX];
        // s=4: (m,m+4), w = TW[16m]
        bf1(e[0], e[4]);
        bf(e[1], e[5], C_TW16); bf(e[2], e[6], C_TW32); bf(e[3], e[7], C_TW48);
        // s=5
        bf1(e[0], e[2]); bf(e[1], e[3], C_TW32);
        bf1(e[4], e[6]); bf(e[5], e[7], C_TW32);
        // s=6
        bf1(e[0], e[1]); bf1(e[2], e[3]); bf1(e[4], e[5]); bf1(e[6], e[7]);
        #pragma unroll
        for (int m = 0; m < 8; ++m) X[it][m] = e[m];
    }
    // no barrier: each thread re-writes only the slots it just read

    const float bv = bias[c];
    float* op = out + (size_t)bc * 65536;

    #pragma unroll 1
    for (int pass = 0; pass < 2; ++pass) {
        const float2* Kp = (pass ? KB : KA) + ((size_t)c << 14);
        // ---- K-mult + inverse col stages 0,1,2 in regs; write rows 8b+m ----
        #pragma unroll
        for (int it = 0; it < 2; ++it) {
            const int rb = 8 * (b0 + 8 * it);
            float2 e[8];
            #pragma unroll
            for (int m = 0; m < 8; ++m)
                e[m] = cmulf(X[it][m], Kp[((rb + m) << 7) + colX]);
            // inv s=0: (m,m+1), w=1
            bi1(e[0],e[1]); bi1(e[2],e[3]); bi1(e[4],e[5]); bi1(e[6],e[7]);
            // inv s=1: (m,m+2), w = conj(TW[32(m&1)])
            bi1(e[0],e[2]); bi(e[1],e[3], C_TW32);
            bi1(e[4],e[6]); bi(e[5],e[7], C_TW32);
            // inv s=2: (m,m+4), w = conj(TW[16m])
            bi1(e[0],e[4]); bi(e[1],e[5], C_TW16);
            bi(e[2],e[6], C_TW32); bi(e[3],e[7], C_TW48);
            #pragma unroll
            for (int m = 0; m < 8; ++m) S[(rb + m) * ST2 + colX] = e[m];
        }
        __syncthreads();

        // ---- inverse col stages 3,4,5,6: radix-16 over rows j+8m ----
        {
            const int col = tid & 127, j = tid >> 7;
            float2 e[16];
            #pragma unroll
            for (int m = 0; m < 16; ++m) e[m] = S[(j + 8*m) * ST2 + col];
            float sj, cj;
            __sincosf(-TWO_PI_N * (float)j, &sj, &cj);
            float2 w1 = make_float2(cj, sj);
            float2 w2 = cmulf(w1, w1);
            float2 w4 = cmulf(w2, w2);
            float2 w8 = cmulf(w4, w4);
            // s=3: (m,m+1), w = conj(TW[8j])
            #pragma unroll
            for (int p = 0; p < 16; p += 2) bi(e[p], e[p+1], w8);
            // s=4: (m,m+2), w = conj(TW[4j+32(m&1)])
            float2 w4b = cmulf(w4, C_TW32);
            #pragma unroll
            for (int q = 0; q < 16; q += 4) {
                bi(e[q+0], e[q+2], w4);
                bi(e[q+1], e[q+3], w4b);
            }
            // s=5: (m,m+4), w = conj(TW[2j+16(m&3)])
            #pragma unroll
            for (int h = 0; h < 16; h += 8) {
                bi(e[h+0], e[h+4], w2);
                bi(e[h+1], e[h+5], cmulf(w2, C_TW16));
                bi(e[h+2], e[h+6], cmulf(w2, C_TW32));
                bi(e[h+3], e[h+7], cmulf(w2, C_TW48));
            }
            // s=6: (m,m+8), w = conj(TW[j+8m])
            bi(e[0], e[8],  w1);
            bi(e[1], e[9],  cmulf(w1, C_TW8));
            bi(e[2], e[10], cmulf(w1, C_TW16));
            bi(e[3], e[11], cmulf(w1, C_TW24));
            bi(e[4], e[12], cmulf(w1, C_TW32));
            bi(e[5], e[13], cmulf(w1, C_TW40));
            bi(e[6], e[14], cmulf(w1, C_TW48));
            bi(e[7], e[15], cmulf(w1, C_TW56));
            #pragma unroll
            for (int m = 0; m < 16; ++m) S[(j + 8*m) * ST2 + col] = e[m];
        }
        __syncthreads();

        // ---- inverse rows stages 0,1,2: two octets, cols 16Q..16Q+15 ----
        {
            const int line = tid >> 3, Q = tid & 7;
            float2* base = &S[line * ST2 + 16 * Q];
            float2 e[16];
            #pragma unroll
            for (int k = 0; k < 8; ++k) {
                float4 v = *(float4*)(base + 2 * k);
                e[2*k]   = make_float2(v.x, v.y);
                e[2*k+1] = make_float2(v.z, v.w);
            }
            #pragma unroll
            for (int o = 0; o < 16; o += 8) {
                bi1(e[o+0],e[o+1]); bi1(e[o+2],e[o+3]); bi1(e[o+4],e[o+5]); bi1(e[o+6],e[o+7]);
                bi1(e[o+0],e[o+2]); bi(e[o+1],e[o+3], C_TW32);
                bi1(e[o+4],e[o+6]); bi(e[o+5],e[o+7], C_TW32);
                bi1(e[o+0],e[o+4]); bi(e[o+1],e[o+5], C_TW16);
                bi(e[o+2],e[o+6], C_TW32); bi(e[o+3],e[o+7], C_TW48);
            }
            #pragma unroll
            for (int k = 0; k < 8; ++k)
                *(float4*)(base + 2 * k) = make_float4(e[2*k].x, e[2*k].y, e[2*k+1].x, e[2*k+1].y);
        }
        __syncthreads();

        // ---- inverse rows stages 3,4,5: dual octet j=2J,2J+1 at cols 64B+j+8m ----
        {
            const int line = tid >> 3, t = tid & 7;
            const int Bq = t >> 2, J = t & 3;
            float2* base = &S[line * ST2 + 64 * Bq + 2 * J];
            float2 e[2][8];
            #pragma unroll
            for (int m = 0; m < 8; ++m) {
                float4 v = *(float4*)(base + 8 * m);
                e[0][m] = make_float2(v.x, v.y);
                e[1][m] = make_float2(v.z, v.w);
            }
            float sj, cj;
            __sincosf(-TWO_PI_N * (float)(2 * J), &sj, &cj);
            float2 w1d[2];
            w1d[0] = make_float2(cj, sj);
            w1d[1] = cmulf(w1d[0], C_TW1);
            #pragma unroll
            for (int d = 0; d < 2; ++d) {
                float2 wa = w1d[d];
                float2 w2 = cmulf(wa, wa);
                float2 w4 = cmulf(w2, w2);
                float2 w8 = cmulf(w4, w4);
                // s=3: (m,m+1), w = conj(TW[8j])
                bi(e[d][0],e[d][1], w8); bi(e[d][2],e[d][3], w8);
                bi(e[d][4],e[d][5], w8); bi(e[d][6],e[d][7], w8);
                // s=4: (m,m+2), w = conj(TW[4j+32(m&1)])
                float2 w4b = cmulf(w4, C_TW32);
                bi(e[d][0],e[d][2], w4); bi(e[d][1],e[d][3], w4b);
                bi(e[d][4],e[d][6], w4); bi(e[d][5],e[d][7], w4b);
                // s=5: (m,m+4), w = conj(TW[2j+16m])
                bi(e[d][0],e[d][4], w2);
                bi(e[d][1],e[d][5], cmulf(w2, C_TW16));
                bi(e[d][2],e[d][6], cmulf(w2, C_TW32));
                bi(e[d][3],e[d][7], cmulf(w2, C_TW48));
            }
            #pragma unroll
            for (int m = 0; m < 8; ++m)
                *(float4*)(base + 8 * m) = make_float4(e[0][m].x, e[0][m].y, e[1][m].x, e[1][m].y);
        }
        __syncthreads();

        // ---- inverse row stage 6 + store (Re->even col, Im->odd col) ----
        #pragma unroll
        for (int it = 0; it < 2; ++it) {
            int g = it * 1024 + tid;
            int line = g >> 4, cc = g & 15;
            float2* base = &S[line * ST2 + 4 * cc];
            float4 va = *(float4*)(base);
            float4 vb = *(float4*)(base + 2);
            float4 vc = *(float4*)(base + 64);
            float4 vd = *(float4*)(base + 66);
            float2 u[4] = { make_float2(va.x,va.y), make_float2(va.z,va.w),
                            make_float2(vb.x,vb.y), make_float2(vb.z,vb.w) };
            float2 v[4] = { make_float2(vc.x,vc.y), make_float2(vc.z,vc.w),
                            make_float2(vd.x,vd.y), make_float2(vd.z,vd.w) };
            float sb_, cb_;
            __sincosf(-TWO_PI_N * (float)(4 * cc), &sb_, &cb_);
            float2 wb = make_float2(cb_, sb_);
            float2 w[4] = { wb, cmulf(wb, C_TW1), cmulf(wb, C_TW2), cmulf(wb, C_TW3) };
            float2 o0[4], o1[4];
            #pragma unroll
            for (int k = 0; k < 4; ++k) {
                float2 tt = cmulcf(v[k], w[k]);
                o0[k] = caddf(u[k], tt);
                o1[k] = csubf(u[k], tt);
            }
            float* orow = op + (size_t)(2 * line + pass) * 256 + 8 * cc;
            ((float4*)orow)[0] = make_float4(o0[0].x+bv, o0[0].y+bv, o0[1].x+bv, o0[1].y+bv);
            ((float4*)orow)[1] = make_float4(o0[2].x+bv, o0[2].y+bv, o0[3].x+bv, o0[3].y+bv);
            float* orow2 = orow + 128;
            ((float4*)orow2)[0] = make_float4(o1[0].x+bv, o1[0].y+bv, o1[1].x+bv, o1[1].y+bv);
            ((float4*)orow2)[1] = make_float4(o1[2].x+bv, o1[2].y+bv, o1[3].x+bv, o1[3].y+bv);
        }
        __syncthreads();   // protect S from next pass's mult writes
    }
}

extern "C" void kernel_launch(void* const* d_in, const int* in_sizes, int n_in,
                              void* d_out, int out_size, void* d_ws, size_t ws_size,
                              hipStream_t stream)
{
    const float* x      = (const float*)d_in[0];   // [4,64,128,128]
    const float* weight = (const float*)d_in[1];   // [1,64,5,5]
    const float* bias   = (const float*)d_in[2];   // [1,64,1,1]
    const float* lam    = (const float*)d_in[3];   // [1,1,1,1]
    float* out = (float*)d_out;                    // [4,64,256,256]

    float2* KA = (float2*)d_ws;                    // 16 MB
    float2* KB = KA + (size_t)64 * 16384;          // 16 MB

    hipLaunchKernelGGL(precompute_K, dim3(512), dim3(256), 0, stream,
                       weight, lam, KA, KB);
    hipLaunchKernelGGL(converse_main, dim3(256), dim3(1024), 0, stream,
                       x, bias, KA, KB, out);
}